// Round 2
// baseline (5640.141 us; speedup 1.0000x reference)
//
#include <hip/hip_runtime.h>
#include <cstdint>
#include <cstddef>

#define NODES   55
#define BGRAPH  16384
#define NTOT    (BGRAPH*NODES)    // 901120
#define INCH    13
#define HID     32
#define ETOT    (4*NTOT)          // 3604480
#define NCHUNK  (NTOT/1024)       // 880 exact

typedef _Float16 f16;
typedef _Float16 f16x8 __attribute__((ext_vector_type(8))); // 16B

__device__ __forceinline__ float selu_f(float v){
  const float s  = 1.0507009873554805f;
  const float sa = 1.7580993408473766f;   // scale*alpha
  return v > 0.f ? s*v : sa*(__expf(v)-1.f);
}

// ---------------- CSR build ----------------
__global__ void k_hist(const int* __restrict__ dst, int* __restrict__ deg){
  int e = blockIdx.x*256 + threadIdx.x;
  if (e < ETOT) atomicAdd(&deg[dst[e]], 1);
}

__global__ void k_scan1(const int* __restrict__ deg, int* __restrict__ part){
  __shared__ int sd[256];
  int b = blockIdx.x, t = threadIdx.x;
  const int4* p = (const int4*)(deg + b*1024);
  int4 v = p[t];
  sd[t] = v.x+v.y+v.z+v.w;
  __syncthreads();
  for (int o=128;o>0;o>>=1){ if (t<o) sd[t]+=sd[t+o]; __syncthreads(); }
  if (t==0) part[b] = sd[0];
}

__global__ void k_scan2(int* __restrict__ part, int nc){
  __shared__ int sd[1024];
  int t = threadIdx.x;
  int orig = (t<nc) ? part[t] : 0;
  sd[t] = orig;
  __syncthreads();
  for (int o=1;o<1024;o<<=1){
    int v = (t>=o) ? sd[t-o] : 0;
    __syncthreads();
    sd[t] += v;
    __syncthreads();
  }
  if (t<nc) part[t] = sd[t] - orig;   // exclusive
}

__global__ void k_scan3(const int* __restrict__ deg, const int* __restrict__ part,
                        int* __restrict__ off){
  __shared__ int sd[256];
  int b = blockIdx.x, t = threadIdx.x;
  const int4* p = (const int4*)(deg + b*1024);
  int4 v = p[t];
  int s = v.x+v.y+v.z+v.w;
  sd[t] = s;
  __syncthreads();
  for (int o=1;o<256;o<<=1){
    int val = (t>=o) ? sd[t-o] : 0;
    __syncthreads();
    sd[t] += val;
    __syncthreads();
  }
  int base = part[b] + sd[t] - s;     // exclusive prefix for this thread
  int i = b*1024 + t*4;
  off[i]   = base;
  off[i+1] = base + v.x;
  off[i+2] = base + v.x + v.y;
  off[i+3] = base + v.x + v.y + v.z;
  if (b==0 && t==0) off[NTOT] = ETOT;
}

__global__ void k_fill(const int* __restrict__ src, const int* __restrict__ dst,
                       int* __restrict__ cur, int* __restrict__ csr){
  int e = blockIdx.x*256 + threadIdx.x;
  if (e >= ETOT) return;
  int d = dst[e];
  int pos = atomicAdd(&cur[d], 1);
  csr[pos] = src[e];
}

// ---------------- SAGE layer 0 ----------------
// 16 threads per node, thread = channel (13 active); x and agg0 are fp32
__global__ __launch_bounds__(256) void k_agg13(const float* __restrict__ x,
                                               const int* __restrict__ off,
                                               const int* __restrict__ csr,
                                               float* __restrict__ agg){
  int t = blockIdx.x*256 + threadIdx.x;
  int node = t >> 4, c = t & 15;
  if (node >= NTOT || c >= INCH) return;
  int s0 = off[node], s1 = off[node+1];
  float s = 0.f;
  for (int e=s0; e<s1; e++){
    int sn = csr[e];
    s += x[(size_t)sn*INCH + c];
  }
  int cnt = s1 - s0; if (cnt < 1) cnt = 1;
  agg[(size_t)node*INCH + c] = s / (float)cnt;
}

// thread = node; weights via uniform scalar loads; outputs fp16
__global__ __launch_bounds__(256) void k_l0(const float* __restrict__ x,
                                            const float* __restrict__ agg,
                                            const float* __restrict__ wl0,
                                            const float* __restrict__ bl0,
                                            const float* __restrict__ wr0,
                                            f16* __restrict__ h,
                                            f16* __restrict__ jk){
  int i = blockIdx.x*256 + threadIdx.x;
  if (i >= NTOT) return;
  float m[INCH], xv[INCH];
  #pragma unroll
  for (int c=0;c<INCH;c++){
    m[c]  = agg[(size_t)i*INCH + c];
    xv[c] = x[(size_t)i*INCH + c];
  }
  float acc[HID];
  #pragma unroll
  for (int oc=0;oc<HID;oc++) acc[oc] = bl0[oc];
  #pragma unroll
  for (int c=0;c<INCH;c++){
    float mc = m[c], xc = xv[c];
    #pragma unroll
    for (int oc=0;oc<HID;oc++)
      acc[oc] = fmaf(xc, wr0[c*HID+oc], fmaf(mc, wl0[c*HID+oc], acc[oc]));
  }
  f16x8* ho = (f16x8*)(h  + (size_t)i*HID);
  f16x8* jo = (f16x8*)(jk + (size_t)i*HID);
  #pragma unroll
  for (int j=0;j<4;j++){
    f16x8 v;
    #pragma unroll
    for (int r=0;r<8;r++) v[r] = (f16)selu_f(acc[8*j+r]);
    ho[j] = v; jo[j] = v;
  }
}

// ---------------- SAGE layers 1..4 ----------------
// 32 threads per node, thread = channel, row-segment gathers (fp16)
__global__ __launch_bounds__(256) void k_agg32(const f16* __restrict__ h,
                                               const int* __restrict__ off,
                                               const int* __restrict__ csr,
                                               f16* __restrict__ agg){
  int t = blockIdx.x*256 + threadIdx.x;
  int node = t >> 5, c = t & 31;
  if (node >= NTOT) return;
  int s0 = off[node], s1 = off[node+1];
  float s = 0.f;
  for (int e=s0; e<s1; e++){
    int sn = csr[e];
    s += (float)h[(size_t)sn*HID + c];
  }
  int cnt = s1 - s0; if (cnt < 1) cnt = 1;
  agg[(size_t)node*HID + c] = (f16)(s / (float)cnt);
}

__global__ __launch_bounds__(256) void k_lt(const f16* __restrict__ agg,
                                            const float* __restrict__ wl,
                                            const float* __restrict__ bl,
                                            const float* __restrict__ wr,
                                            f16* __restrict__ h,
                                            f16* __restrict__ jk){
  int i = blockIdx.x*256 + threadIdx.x;
  if (i >= NTOT) return;
  const f16x8* a8 = (const f16x8*)(agg + (size_t)i*HID);
  const f16x8* h8 = (const f16x8*)(h   + (size_t)i*HID);
  float m[HID], hv[HID];
  #pragma unroll
  for (int j=0;j<4;j++){
    f16x8 va = a8[j], vh = h8[j];
    #pragma unroll
    for (int r=0;r<8;r++){ m[8*j+r] = (float)va[r]; hv[8*j+r] = (float)vh[r]; }
  }
  float acc[HID];
  #pragma unroll
  for (int oc=0;oc<HID;oc++) acc[oc] = bl[oc];
  #pragma unroll
  for (int c=0;c<HID;c++){
    float mc = m[c], hc = hv[c];
    #pragma unroll
    for (int oc=0;oc<HID;oc++)
      acc[oc] = fmaf(hc, wr[c*HID+oc], fmaf(mc, wl[c*HID+oc], acc[oc]));
  }
  f16x8* ho = (f16x8*)(h  + (size_t)i*HID);
  f16x8* jo = (f16x8*)(jk + (size_t)i*HID);
  #pragma unroll
  for (int j=0;j<4;j++){
    f16x8 vcur = jo[j];
    f16x8 vh, vj;
    #pragma unroll
    for (int r=0;r<8;r++){
      float sv = selu_f(acc[8*j+r]);
      vh[r] = (f16)sv;
      float jv = (float)vcur[r];
      vj[r] = (f16)fmaxf(jv, sv);
    }
    ho[j] = vh; jo[j] = vj;
  }
}

// ---------------- attention + head, one block per graph ----------------
__global__ __launch_bounds__(256) void k_attn(
    const f16* __restrict__ jk, const float* __restrict__ x,
    const int* __restrict__ shuf,
    const float* __restrict__ wq, const float* __restrict__ bq,
    const float* __restrict__ wk, const float* __restrict__ bk,
    const float* __restrict__ wv, const float* __restrict__ bv,
    const float* __restrict__ wo, const float* __restrict__ bo,
    const float* __restrict__ wfc, const float* __restrict__ bfc,
    float* __restrict__ out)
{
  __shared__ float H[NODES*33];
  __shared__ float K[NODES*33];
  __shared__ float V[NODES*33];
  __shared__ float Wq[HID*HID];
  __shared__ float Wo[HID*HID];
  __shared__ float Wfc[192*6];
  __shared__ float Qs[6*33];
  __shared__ float S[6*56];
  __shared__ float O[6*33];
  __shared__ float SO[192];
  __shared__ float part[96];
  __shared__ float M[NODES];
  __shared__ int order[8];
  __shared__ int sel[6];

  int g = blockIdx.x, t = threadIdx.x;
  for (int i=t; i<HID*HID; i+=256){ Wq[i]=wq[i]; Wo[i]=wo[i]; }
  for (int i=t; i<192*6;   i+=256){ Wfc[i]=wfc[i]; }
  {
    const f16x8* j8 = (const f16x8*)(jk + (size_t)g*NODES*HID);
    for (int i=t; i<NODES*HID/8; i+=256){     // 220 vectors of 8
      f16x8 v = j8[i];
      int node = i >> 2, c0 = (i & 3)*8;
      #pragma unroll
      for (int r=0;r<8;r++) H[node*33 + c0 + r] = selu_f((float)v[r]);
    }
  }
  if (t < NODES) M[t] = x[(size_t)(g*NODES+t)*INCH + (INCH-3)];
  __syncthreads();
  if (t == 0){
    int c = 0;
    for (int n=0;n<NODES;n++) if (M[n] > 0.5f && c < 6) order[c++] = n;
  }
  __syncthreads();
  if (t < 6) sel[t] = order[shuf[g*6 + t]];
  __syncthreads();

  // K and V: lane = node, wave-uniform output-channel group -> scalar weights
  {
    int k = t & 63;
    int ocg = __builtin_amdgcn_readfirstlane(t >> 6);   // 0..3, wave-uniform
    const float* wkp = wk + ocg*8;
    const float* wvp = wv + ocg*8;
    if (k < NODES){
      float ak[8], av[8];
      #pragma unroll
      for (int j=0;j<8;j++){ ak[j]=bk[ocg*8+j]; av[j]=bv[ocg*8+j]; }
      #pragma unroll
      for (int c=0;c<HID;c++){
        float hv = H[k*33+c];
        #pragma unroll
        for (int j=0;j<8;j++){
          ak[j] = fmaf(hv, wkp[c*HID+j], ak[j]);
          av[j] = fmaf(hv, wvp[c*HID+j], av[j]);
        }
      }
      #pragma unroll
      for (int j=0;j<8;j++){ K[k*33+ocg*8+j]=ak[j]; V[k*33+ocg*8+j]=av[j]; }
    }
  }
  // Q: 6 queries x 32 channels
  if (t < 192){
    int q = t>>5, oc = t&31;
    int node = sel[q];
    float a = bq[oc];
    #pragma unroll
    for (int c=0;c<HID;c++) a = fmaf(H[node*33+c], Wq[c*HID+oc], a);
    Qs[q*33+oc] = a;
  }
  __syncthreads();

  // scores = Q.K^T / sqrt(32)
  for (int idx=t; idx<6*NODES; idx+=256){
    int q = idx % 6, k = idx / 6;
    float a = 0.f;
    #pragma unroll
    for (int c=0;c<HID;c++) a = fmaf(Qs[q*33+c], K[k*33+c], a);
    S[q*56+k] = a * 0.17677669529663687f;
  }
  __syncthreads();

  // softmax over 55 keys: 32-lane group per query
  if (t < 192){
    int q = t>>5, l = t&31;
    float v0 = (l      < NODES) ? S[q*56+l]    : -1e30f;
    float v1 = (l+32   < NODES) ? S[q*56+l+32] : -1e30f;
    float mx = fmaxf(v0, v1);
    #pragma unroll
    for (int o=16;o>0;o>>=1) mx = fmaxf(mx, __shfl_xor(mx, o, 32));
    float p0 = (l    < NODES) ? __expf(v0-mx) : 0.f;
    float p1 = (l+32 < NODES) ? __expf(v1-mx) : 0.f;
    float sm = p0 + p1;
    #pragma unroll
    for (int o=16;o>0;o>>=1) sm += __shfl_xor(sm, o, 32);
    float inv = 1.f/sm;
    if (l    < NODES) S[q*56+l]    = p0*inv;
    if (l+32 < NODES) S[q*56+l+32] = p1*inv;
  }
  __syncthreads();

  // attn @ V
  if (t < 192){
    int q = t>>5, oc = t&31;
    float a = 0.f;
    for (int k=0;k<NODES;k++) a = fmaf(S[q*56+k], V[k*33+oc], a);
    O[q*33+oc] = a;
  }
  __syncthreads();

  // @ wo + bo, selu
  if (t < 192){
    int q = t>>5, oc = t&31;
    float a = bo[oc];
    #pragma unroll
    for (int c=0;c<HID;c++) a = fmaf(O[q*33+c], Wo[c*HID+oc], a);
    SO[t] = selu_f(a);   // t == q*32+oc == flat reshape index
  }
  __syncthreads();

  // final FC: 6 outputs = SO[192] . Wfc[:,j]
  if (t < 96){
    int j = t % 6, pp = t / 6;   // 16 partials per output
    float a = 0.f;
    #pragma unroll
    for (int r=0;r<12;r++) a = fmaf(SO[pp*12+r], Wfc[(pp*12+r)*6+j], a);
    part[pp*6+j] = a;
  }
  __syncthreads();
  if (t < 6){
    float a = bfc[t];
    #pragma unroll
    for (int pp=0;pp<16;pp++) a += part[pp*6+t];
    out[g*6+t] = a;
  }
}

extern "C" void kernel_launch(void* const* d_in, const int* in_sizes, int n_in,
                              void* d_out, int out_size, void* d_ws, size_t ws_size,
                              hipStream_t stream)
{
  const float* x   = (const float*)d_in[0];
  const int*   eix = (const int*)d_in[1];
  const int*   shf = (const int*)d_in[2];
  const float* wl0 = (const float*)d_in[3];
  const float* bl0 = (const float*)d_in[4];
  const float* wr0 = (const float*)d_in[5];
  const float* wl  = (const float*)d_in[6];
  const float* bl  = (const float*)d_in[7];
  const float* wr  = (const float*)d_in[8];
  const float* wq  = (const float*)d_in[9];
  const float* bq  = (const float*)d_in[10];
  const float* wk  = (const float*)d_in[11];
  const float* bk  = (const float*)d_in[12];
  const float* wv  = (const float*)d_in[13];
  const float* bv  = (const float*)d_in[14];
  const float* wo  = (const float*)d_in[15];
  const float* bo  = (const float*)d_in[16];
  const float* wfc = (const float*)d_in[17];
  const float* bfc = (const float*)d_in[18];
  float* out = (float*)d_out;

  const int* esrc = eix;
  const int* edst = eix + ETOT;

  // workspace carve — total ~195 MB (fp16 intermediates)
  char* p = (char*)d_ws;
  auto carve = [&](size_t bytes){ void* r = (void*)p; p += (bytes + 255) & ~(size_t)255; return r; };
  int*   deg  = (int*)carve(sizeof(int)*NTOT);          // reused as `cur` for k_fill
  int*   off  = (int*)carve(sizeof(int)*(NTOT+1));
  int*   part = (int*)carve(sizeof(int)*1024);
  int*   csr  = (int*)carve(sizeof(int)*(size_t)ETOT);
  void*  aggv = carve(2*(size_t)NTOT*HID);              // fp16[N*32] OR fp32[N*13] (46.9MB < 57.7MB)
  f16*   h16  = (f16*)carve(2*(size_t)NTOT*HID);
  f16*   jk16 = (f16*)carve(2*(size_t)NTOT*HID);
  f16*   agg16 = (f16*)aggv;
  float* aggF  = (float*)aggv;

  hipMemsetAsync(deg, 0, sizeof(int)*NTOT, stream);
  k_hist <<<ETOT/256,  256, 0, stream>>>(edst, deg);
  k_scan1<<<NCHUNK,    256, 0, stream>>>(deg, part);
  k_scan2<<<1,        1024, 0, stream>>>(part, NCHUNK);
  k_scan3<<<NCHUNK,    256, 0, stream>>>(deg, part, off);
  // reuse deg as the fill cursor
  hipMemcpyAsync(deg, off, sizeof(int)*NTOT, hipMemcpyDeviceToDevice, stream);
  k_fill <<<ETOT/256,  256, 0, stream>>>(esrc, edst, deg, csr);

  k_agg13<<<NTOT/16,   256, 0, stream>>>(x, off, csr, aggF);
  k_l0   <<<NTOT/256,  256, 0, stream>>>(x, aggF, wl0, bl0, wr0, h16, jk16);
  for (int l=0; l<4; l++){
    k_agg32<<<NTOT/8,   256, 0, stream>>>(h16, off, csr, agg16);
    k_lt   <<<NTOT/256, 256, 0, stream>>>(agg16, wl + l*HID*HID, bl + l*HID, wr + l*HID*HID, h16, jk16);
  }
  k_attn<<<BGRAPH, 256, 0, stream>>>(jk16, x, shf,
                                     wq, bq, wk, bk, wv, bv, wo, bo, wfc, bfc, out);
}